// Round 5
// baseline (337.617 us; speedup 1.0000x reference)
//
#include <hip/hip_runtime.h>
#include <hip/hip_bf16.h>
#include <cstdint>
#include <cstddef>

#define SEQ    2048
#define DMODEL 1024
#define DEXP   2048
#define NHEADS 16
#define DHEAD  128

typedef __bf16 bf16x8 __attribute__((ext_vector_type(8)));
typedef float  f32x4  __attribute__((ext_vector_type(4)));

__device__ __forceinline__ unsigned short f2bf(float f) {
  unsigned int u = __builtin_bit_cast(unsigned int, f);
  u = u + 0x7FFFu + ((u >> 16) & 1u);   // round-to-nearest-even
  return (unsigned short)(u >> 16);
}
__device__ __forceinline__ float bf2f(unsigned short h) {
  unsigned int u = ((unsigned int)h) << 16;
  return __builtin_bit_cast(float, u);
}

__device__ __forceinline__ void gload_lds16(const void* g, void* l) {
  __builtin_amdgcn_global_load_lds(
      (const __attribute__((address_space(1))) unsigned int*)g,
      (__attribute__((address_space(3))) unsigned int*)l, 16, 0, 0);
}

// ---------------- LayerNorm (one row of 1024 per block, 256 threads) ----------------
__global__ __launch_bounds__(256) void ln_kernel(const float* __restrict__ in,
    const float* __restrict__ gw, const float* __restrict__ gb,
    unsigned short* __restrict__ out_bf, float* __restrict__ out_f) {
  int row = blockIdx.x, t = threadIdx.x;
  const float4* ip = reinterpret_cast<const float4*>(in + (size_t)row * DMODEL);
  float4 v = ip[t];
  float s  = v.x + v.y + v.z + v.w;
  float ss = v.x*v.x + v.y*v.y + v.z*v.z + v.w*v.w;
  #pragma unroll
  for (int m = 1; m < 64; m <<= 1) { s += __shfl_xor(s, m, 64); ss += __shfl_xor(ss, m, 64); }
  __shared__ float sh[8];
  if ((t & 63) == 0) { sh[t >> 6] = s; sh[4 + (t >> 6)] = ss; }
  __syncthreads();
  s  = sh[0] + sh[1] + sh[2] + sh[3];
  ss = sh[4] + sh[5] + sh[6] + sh[7];
  float mu  = s * (1.0f / DMODEL);
  float var = ss * (1.0f / DMODEL) - mu * mu;
  float rs  = rsqrtf(var + 1e-5f);
  float4 w4 = reinterpret_cast<const float4*>(gw)[t];
  float4 b4 = reinterpret_cast<const float4*>(gb)[t];
  float o0 = (v.x - mu) * rs * w4.x + b4.x;
  float o1 = (v.y - mu) * rs * w4.y + b4.y;
  float o2 = (v.z - mu) * rs * w4.z + b4.z;
  float o3 = (v.w - mu) * rs * w4.w + b4.w;
  if (out_bf) {
    unsigned short* op = out_bf + (size_t)row * DMODEL + t * 4;
    op[0] = f2bf(o0); op[1] = f2bf(o1); op[2] = f2bf(o2); op[3] = f2bf(o3);
  } else {
    float4 o4; o4.x = o0; o4.y = o1; o4.z = o2; o4.w = o3;
    reinterpret_cast<float4*>(out_f + (size_t)row * DMODEL)[t] = o4;
  }
}

// ---------------- f32 -> bf16 cast, 4 elems/thread ----------------
__global__ void castbf4(const float* __restrict__ in, unsigned short* __restrict__ out, int n4) {
  int i = blockIdx.x * 256 + threadIdx.x;
  if (i >= n4) return;
  float4 v = reinterpret_cast<const float4*>(in)[i];
  ushort4 o;
  o.x = f2bf(v.x); o.y = f2bf(v.y); o.z = f2bf(v.z); o.w = f2bf(v.w);
  reinterpret_cast<ushort4*>(out)[i] = o;
}

// ---------------- GEMM  C[M,N] = A[M,K] * B[N,K]^T,  LDS-staged (m97 structure) ----------
template<int EPI>
__global__ __launch_bounds__(256) void gemm_lds(
    const unsigned short* __restrict__ A, const unsigned short* __restrict__ B,
    int M, int N, int K,
    const float* __restrict__ b_in, const float* __restrict__ log_scale,
    unsigned short* __restrict__ outq, unsigned short* __restrict__ outk,
    unsigned short* __restrict__ outvt, unsigned short* __restrict__ outp,
    float* __restrict__ outf) {
  int nbn = N / 128;
  int bm = blockIdx.x / nbn, bn = blockIdx.x % nbn;
  int tid = threadIdx.x;
  int wid = tid >> 6, l = tid & 63;
  int wr = wid >> 1, wc = wid & 1;
  int row0 = bm * 128, col0 = bn * 128;
  int c16 = l & 15, g = l >> 4;
  int srow = l >> 2;
  int skb  = (l & 3) * 8;

  __shared__ __align__(16) unsigned short As[128 * 32];
  __shared__ __align__(16) unsigned short Bs[128 * 32];

  f32x4 acc[4][4];
  f32x4 z = {0.f, 0.f, 0.f, 0.f};
  #pragma unroll
  for (int i = 0; i < 4; ++i)
    #pragma unroll
    for (int j = 0; j < 4; ++j) acc[i][j] = z;

  for (int k0 = 0; k0 < K; k0 += 32) {
    #pragma unroll
    for (int qq = 0; qq < 2; ++qq) {
      int t = wid * 2 + qq;
      gload_lds16(A + (size_t)(row0 + t * 16 + srow) * K + k0 + skb, As + t * 512);
      gload_lds16(B + (size_t)(col0 + t * 16 + srow) * K + k0 + skb, Bs + t * 512);
    }
    __syncthreads();
    bf16x8 a[4], b[4];
    #pragma unroll
    for (int i = 0; i < 4; ++i)
      a[i] = *reinterpret_cast<const bf16x8*>(As + (wr * 64 + i * 16 + c16) * 32 + g * 8);
    #pragma unroll
    for (int j = 0; j < 4; ++j)
      b[j] = *reinterpret_cast<const bf16x8*>(Bs + (wc * 64 + j * 16 + c16) * 32 + g * 8);
    #pragma unroll
    for (int i = 0; i < 4; ++i)
      #pragma unroll
      for (int j = 0; j < 4; ++j)
        acc[i][j] = __builtin_amdgcn_mfma_f32_16x16x32_bf16(a[i], b[j], acc[i][j], 0, 0, 0);
    __syncthreads();
  }

  #pragma unroll
  for (int i = 0; i < 4; ++i) {
    #pragma unroll
    for (int j = 0; j < 4; ++j) {
      #pragma unroll
      for (int r = 0; r < 4; ++r) {
        int gi = row0 + wr * 64 + i * 16 + g * 4 + r;
        int n  = col0 + wc * 64 + j * 16 + c16;
        float val = acc[i][j][r];
        if constexpr (EPI == 0) {
          val += b_in[n];
          int sec = n >> 11, nn = n & 2047, hh = nn >> 7;
          if (sec == 0) {
            float qs = __expf(-2.f * log_scale[hh]) * 0.088388347648318447f; // 1/(s^2*sqrt(128))
            outq[(size_t)gi * DEXP + nn] = f2bf(val * qs);
          } else if (sec == 1) {
            outk[(size_t)gi * DEXP + nn] = f2bf(val);
          } else if (sec == 2) {
            outvt[(size_t)nn * SEQ + gi] = f2bf(val);   // V transposed: vt[h*128+d][i]
          } else {
            outp[(size_t)gi * DEXP + nn] = f2bf(val);
          }
        } else {
          outf[(size_t)gi * N + n] = val;
        }
      }
    }
  }
}

// ---------------- y head ----------------
__global__ __launch_bounds__(256) void yproj(const unsigned short* __restrict__ xn,
    const unsigned short* __restrict__ winbf, const float* __restrict__ b_in,
    float* __restrict__ sig_y) {
  int i = blockIdx.x;
  int t = threadIdx.x, wv = t >> 6, l = t & 63;
  const unsigned short* xr = xn + (size_t)i * DMODEL;
  for (int h = wv; h < NHEADS; h += 4) {
    const unsigned short* wr = winbf + (size_t)(4 * DEXP + h) * DMODEL;
    float s = 0.f;
    #pragma unroll
    for (int e = 0; e < 16; ++e) {
      int idx = l + 64 * e;
      s += bf2f(xr[idx]) * bf2f(wr[idx]);
    }
    #pragma unroll
    for (int m = 1; m < 64; m <<= 1) s += __shfl_xor(s, m, 64);
    if (l == 0) {
      float yv = s + b_in[4 * DEXP + h];
      sig_y[h * SEQ + i] = 1.f / (1.f + __expf(-yv));
    }
  }
}

// ---------------- inclusive scan of sig_y per head -> pos[h][i] ----------------
__global__ __launch_bounds__(256) void scan_kernel(const float* __restrict__ sig_y,
                                                   float* __restrict__ pos) {
  int h = blockIdx.x, t = threadIdx.x;
  const float* in = sig_y + (size_t)h * SEQ;
  float v[8], s = 0.f;
  #pragma unroll
  for (int e = 0; e < 8; ++e) { v[e] = in[t * 8 + e]; s += v[e]; }
  __shared__ float sh[256];
  sh[t] = s;
  __syncthreads();
  for (int off = 1; off < 256; off <<= 1) {
    float add = (t >= off) ? sh[t - off] : 0.f;
    __syncthreads();
    sh[t] += add;
    __syncthreads();
  }
  float run = sh[t] - s;
  float* op = pos + (size_t)h * SEQ;
  #pragma unroll
  for (int e = 0; e < 8; ++e) { run += v[e]; op[t * 8 + e] = run; }
}

// ---------------- smear ----------------
__global__ void smear_kernel(const unsigned short* __restrict__ projk,
    const float* __restrict__ smearf, unsigned short* __restrict__ ksm) {
  int idx = blockIdx.x * 256 + threadIdx.x;
  if (idx >= SEQ * DEXP) return;
  int i = idx >> 11, nn = idx & 2047, h = nn >> 7;
  float sf = 1.f / (1.f + __expf(-smearf[h]));
  float kc = bf2f(projk[idx]);
  float kp = (i > 0) ? bf2f(projk[idx - DEXP]) : 0.f;
  ksm[idx] = f2bf((1.f - sf) * kc + sf * kp);
}

// ---------------- flash attention: 4-wave block, j-split + split-merge ----------------
// Block handles (h, 16-row q-tile qt). Wave w processes jt = w, w+4, ... independently
// with its own online softmax; partials merged at the end via LDS.
// NOTE: P_lds write -> cross-lane read is intra-wave; ordering enforced by the
// inline-asm lgkmcnt(0) fence + sched_barrier (no __syncthreads possible: waves
// have unequal trip counts).
__global__ __launch_bounds__(256) void attn_kernel(
    const unsigned short* __restrict__ q, const unsigned short* __restrict__ ksm,
    const unsigned short* __restrict__ vt, const unsigned short* __restrict__ projp,
    const float* __restrict__ pos, unsigned short* __restrict__ ap) {
  int bid = blockIdx.x;
  int swz = (bid & 7) * 256 + (bid >> 3);    // bijective XCD swizzle: 2 heads per XCD
  int h = swz >> 7, qt = swz & 127;
  int tid = threadIdx.x;
  int wid = tid >> 6, l = tid & 63;
  int c16 = l & 15, g = l >> 4;

  __shared__ __align__(16) unsigned short P_lds[4][16 * 36];   // per-wave private
  __shared__ float ml[4][2][16];
  __shared__ float ob[4][16][17];

  bf16x8 qf[4];
  {
    const unsigned short* qb = q + (size_t)(qt * 16 + c16) * DEXP + h * DHEAD + g * 8;
    #pragma unroll
    for (int f = 0; f < 4; ++f) qf[f] = *reinterpret_cast<const bf16x8*>(qb + f * 32);
  }
  float pos_i[4];
  #pragma unroll
  for (int r = 0; r < 4; ++r) pos_i[r] = pos[h * SEQ + qt * 16 + g * 4 + r];
  float m_run[4], l_run[4];
  #pragma unroll
  for (int r = 0; r < 4; ++r) { m_run[r] = -1e30f; l_run[r] = 0.f; }
  f32x4 oacc[8];
  f32x4 z = {0.f, 0.f, 0.f, 0.f};
  #pragma unroll
  for (int nb = 0; nb < 8; ++nb) oacc[nb] = z;

  int jtmax = (qt * 16 + 15) >> 5;
  for (int jt = wid; jt <= jtmax; jt += 4) {
    int j0 = jt * 32;
    f32x4 s0 = z, s1 = z;
    {
      const unsigned short* kb0 = ksm + (size_t)(j0 + c16) * DEXP + h * DHEAD + g * 8;
      __builtin_amdgcn_s_setprio(1);
      #pragma unroll
      for (int f = 0; f < 4; ++f) {
        bf16x8 k0v = *reinterpret_cast<const bf16x8*>(kb0 + f * 32);
        bf16x8 k1v = *reinterpret_cast<const bf16x8*>(kb0 + (size_t)16 * DEXP + f * 32);
        s0 = __builtin_amdgcn_mfma_f32_16x16x32_bf16(qf[f], k0v, s0, 0, 0, 0);
        s1 = __builtin_amdgcn_mfma_f32_16x16x32_bf16(qf[f], k1v, s1, 0, 0, 0);
      }
      __builtin_amdgcn_s_setprio(0);
    }
    float pj0 = pos[h * SEQ + j0 + c16];
    float pj1 = pos[h * SEQ + j0 + 16 + c16];
    float v0[4], v1[4], mt[4];
    #pragma unroll
    for (int r = 0; r < 4; ++r) {
      int row = qt * 16 + g * 4 + r;
      int col0 = j0 + c16, col1 = col0 + 16;
      float a0 = s0[r] - pos_i[r] + pj0 + (col0 > row ? -1e10f : 0.f);
      float a1 = s1[r] - pos_i[r] + pj1 + (col1 > row ? -1e10f : 0.f);
      v0[r] = a0; v1[r] = a1;
      mt[r] = fmaxf(a0, a1);
    }
    #pragma unroll
    for (int r = 0; r < 4; ++r)
      #pragma unroll
      for (int m = 1; m < 16; m <<= 1)
        mt[r] = fmaxf(mt[r], __shfl_xor(mt[r], m, 64));
    float alpha[4], ps[4];
    #pragma unroll
    for (int r = 0; r < 4; ++r) {
      float mn = fmaxf(m_run[r], mt[r]);
      alpha[r] = __expf(m_run[r] - mn);
      m_run[r] = mn;
      float p0 = __expf(v0[r] - mn);
      float p1 = __expf(v1[r] - mn);
      P_lds[wid][(g * 4 + r) * 36 + c16]      = f2bf(p0);
      P_lds[wid][(g * 4 + r) * 36 + 16 + c16] = f2bf(p1);
      ps[r] = p0 + p1;
    }
    // Fence: make the P ds_writes land before the cross-lane ds_read below.
    asm volatile("s_waitcnt lgkmcnt(0)" ::: "memory");
    __builtin_amdgcn_sched_barrier(0);
    #pragma unroll
    for (int r = 0; r < 4; ++r) {
      #pragma unroll
      for (int m = 1; m < 16; m <<= 1) ps[r] += __shfl_xor(ps[r], m, 64);
      l_run[r] = l_run[r] * alpha[r] + ps[r];
    }
    #pragma unroll
    for (int nb = 0; nb < 8; ++nb)
      #pragma unroll
      for (int r = 0; r < 4; ++r) oacc[nb][r] *= alpha[r];
    // P as A-fragment (wave-private LDS round trip)
    union { unsigned long long u[2]; bf16x8 v; } pa;
    const unsigned long long* pl =
        reinterpret_cast<const unsigned long long*>(&P_lds[wid][c16 * 36 + g * 8]);
    pa.u[0] = pl[0]; pa.u[1] = pl[1];
    const unsigned short* vb0 = vt + (size_t)(h * DHEAD + c16) * SEQ + j0 + g * 8;
    __builtin_amdgcn_s_setprio(1);
    #pragma unroll
    for (int nb = 0; nb < 8; ++nb) {
      bf16x8 vf = *reinterpret_cast<const bf16x8*>(vb0 + (size_t)nb * 16 * SEQ);
      oacc[nb] = __builtin_amdgcn_mfma_f32_16x16x32_bf16(pa.v, vf, oacc[nb], 0, 0, 0);
    }
    __builtin_amdgcn_s_setprio(0);
  }

  // ---- cross-wave merge: M = max m_w, L = sum l_w exp(m_w - M), O = sum o_w exp(m_w - M)
  if (c16 == 0) {
    #pragma unroll
    for (int r = 0; r < 4; ++r) {
      ml[wid][0][g * 4 + r] = m_run[r];
      ml[wid][1][g * 4 + r] = l_run[r];
    }
  }
  __syncthreads();
  float Lr[4], sc[4];
  #pragma unroll
  for (int r = 0; r < 4; ++r) {
    int row = g * 4 + r;
    float m0 = ml[0][0][row], m1 = ml[1][0][row], m2 = ml[2][0][row], m3 = ml[3][0][row];
    float M = fmaxf(fmaxf(m0, m1), fmaxf(m2, m3));
    Lr[r] = ml[0][1][row] * __expf(m0 - M) + ml[1][1][row] * __expf(m1 - M)
          + ml[2][1][row] * __expf(m2 - M) + ml[3][1][row] * __expf(m3 - M);
    sc[r] = __expf(m_run[r] - M);     // idle wave: exp(-1e30 - M) = 0
  }
  #pragma unroll
  for (int nb = 0; nb < 8; ++nb) {
    #pragma unroll
    for (int r = 0; r < 4; ++r) ob[wid][g * 4 + r][c16] = oacc[nb][r] * sc[r];
    __syncthreads();
    if (wid == (nb & 3)) {
      #pragma unroll
      for (int r = 0; r < 4; ++r) {
        int lr = g * 4 + r;
        float tot = ob[0][lr][c16] + ob[1][lr][c16] + ob[2][lr][c16] + ob[3][lr][c16];
        int row = qt * 16 + lr;
        int nn = h * DHEAD + nb * 16 + c16;
        float o = tot / Lr[r];
        float pv = bf2f(projp[(size_t)row * DEXP + nn]);
        float si = pv / (1.f + __expf(-pv));
        ap[(size_t)row * DEXP + nn] = f2bf(si * o);
      }
    }
    __syncthreads();
  }
}

extern "C" void kernel_launch(void* const* d_in, const int* in_sizes, int n_in,
                              void* d_out, int out_size, void* d_ws, size_t ws_size,
                              hipStream_t stream) {
  const float* x         = (const float*)d_in[0];
  const float* W_in      = (const float*)d_in[1];
  const float* b_in      = (const float*)d_in[2];
  const float* in_ln_w   = (const float*)d_in[3];
  const float* in_ln_b   = (const float*)d_in[4];
  const float* W_out     = (const float*)d_in[5];
  const float* out_ln_w  = (const float*)d_in[6];
  const float* out_ln_b  = (const float*)d_in[7];
  const float* smearf    = (const float*)d_in[8];
  const float* log_scale = (const float*)d_in[9];
  float* out = (float*)d_out;

  char* ws = (char*)d_ws;
  size_t off = 0;
  auto alloc = [&](size_t bytes) -> void* {
    void* p = ws + off;
    off += (bytes + 255) & ~(size_t)255;
    return p;
  };
  unsigned short* xn     = (unsigned short*)alloc((size_t)SEQ * DMODEL * 2);
  unsigned short* winbf  = (unsigned short*)alloc((size_t)(4 * DEXP + NHEADS) * DMODEL * 2);
  unsigned short* woutbf = (unsigned short*)alloc((size_t)DMODEL * DEXP * 2);
  unsigned short* projq  = (unsigned short*)alloc((size_t)SEQ * DEXP * 2);
  unsigned short* projk  = (unsigned short*)alloc((size_t)SEQ * DEXP * 2);
  unsigned short* projp  = (unsigned short*)alloc((size_t)SEQ * DEXP * 2);
  unsigned short* vtb    = (unsigned short*)alloc((size_t)SEQ * DEXP * 2);
  unsigned short* ksm    = (unsigned short*)alloc((size_t)SEQ * DEXP * 2);
  unsigned short* apb    = (unsigned short*)alloc((size_t)SEQ * DEXP * 2);
  float* sig_y = (float*)alloc((size_t)NHEADS * SEQ * 4);
  float* posb  = (float*)alloc((size_t)NHEADS * SEQ * 4);
  float* outf  = (float*)alloc((size_t)SEQ * DMODEL * 4);

  int nwin4  = (4 * DEXP + NHEADS) * DMODEL / 4;
  int nwout4 = DMODEL * DEXP / 4;
  castbf4<<<(nwin4 + 255) / 256, 256, 0, stream>>>(W_in, winbf, nwin4);
  castbf4<<<(nwout4 + 255) / 256, 256, 0, stream>>>(W_out, woutbf, nwout4);
  ln_kernel<<<SEQ, 256, 0, stream>>>(x, in_ln_w, in_ln_b, xn, nullptr);
  gemm_lds<0><<<(SEQ / 128) * (4 * DEXP / 128), 256, 0, stream>>>(
      xn, winbf, SEQ, 4 * DEXP, DMODEL, b_in, log_scale, projq, projk, vtb, projp, nullptr);
  yproj<<<SEQ, 256, 0, stream>>>(xn, winbf, b_in, sig_y);
  scan_kernel<<<NHEADS, 256, 0, stream>>>(sig_y, posb);
  smear_kernel<<<(SEQ * DEXP + 255) / 256, 256, 0, stream>>>(projk, smearf, ksm);
  attn_kernel<<<NHEADS * 128, 256, 0, stream>>>(projq, ksm, vtb, projp, posb, apb);
  gemm_lds<1><<<(SEQ / 128) * (DMODEL / 128), 256, 0, stream>>>(
      apb, woutbf, SEQ, DMODEL, DEXP, nullptr, nullptr, nullptr, nullptr, nullptr, nullptr, outf);
  ln_kernel<<<SEQ, 256, 0, stream>>>(outf, out_ln_w, out_ln_b, nullptr, out);
}

// Round 6
// 295.727 us; speedup vs baseline: 1.1417x; 1.1417x over previous
//
#include <hip/hip_runtime.h>
#include <hip/hip_bf16.h>
#include <cstdint>
#include <cstddef>

#define SEQ    2048
#define DMODEL 1024
#define DEXP   2048
#define NHEADS 16
#define DHEAD  128

typedef __bf16 bf16x8 __attribute__((ext_vector_type(8)));
typedef float  f32x4  __attribute__((ext_vector_type(4)));

__device__ __forceinline__ unsigned short f2bf(float f) {
  unsigned int u = __builtin_bit_cast(unsigned int, f);
  u = u + 0x7FFFu + ((u >> 16) & 1u);   // round-to-nearest-even
  return (unsigned short)(u >> 16);
}
__device__ __forceinline__ float bf2f(unsigned short h) {
  unsigned int u = ((unsigned int)h) << 16;
  return __builtin_bit_cast(float, u);
}
__device__ __forceinline__ unsigned int pk2bf(float a, float b) {
  return ((unsigned int)f2bf(b) << 16) | f2bf(a);
}

__device__ __forceinline__ void gload_lds16(const void* g, void* l) {
  __builtin_amdgcn_global_load_lds(
      (const __attribute__((address_space(1))) unsigned int*)g,
      (__attribute__((address_space(3))) unsigned int*)l, 16, 0, 0);
}

// ---------------- LayerNorm (one row of 1024 per block, 256 threads) ----------------
__global__ __launch_bounds__(256) void ln_kernel(const float* __restrict__ in,
    const float* __restrict__ gw, const float* __restrict__ gb,
    unsigned short* __restrict__ out_bf, float* __restrict__ out_f) {
  int row = blockIdx.x, t = threadIdx.x;
  const float4* ip = reinterpret_cast<const float4*>(in + (size_t)row * DMODEL);
  float4 v = ip[t];
  float s  = v.x + v.y + v.z + v.w;
  float ss = v.x*v.x + v.y*v.y + v.z*v.z + v.w*v.w;
  #pragma unroll
  for (int m = 1; m < 64; m <<= 1) { s += __shfl_xor(s, m, 64); ss += __shfl_xor(ss, m, 64); }
  __shared__ float sh[8];
  if ((t & 63) == 0) { sh[t >> 6] = s; sh[4 + (t >> 6)] = ss; }
  __syncthreads();
  s  = sh[0] + sh[1] + sh[2] + sh[3];
  ss = sh[4] + sh[5] + sh[6] + sh[7];
  float mu  = s * (1.0f / DMODEL);
  float var = ss * (1.0f / DMODEL) - mu * mu;
  float rs  = rsqrtf(var + 1e-5f);
  float4 w4 = reinterpret_cast<const float4*>(gw)[t];
  float4 b4 = reinterpret_cast<const float4*>(gb)[t];
  float o0 = (v.x - mu) * rs * w4.x + b4.x;
  float o1 = (v.y - mu) * rs * w4.y + b4.y;
  float o2 = (v.z - mu) * rs * w4.z + b4.z;
  float o3 = (v.w - mu) * rs * w4.w + b4.w;
  if (out_bf) {
    unsigned short* op = out_bf + (size_t)row * DMODEL + t * 4;
    op[0] = f2bf(o0); op[1] = f2bf(o1); op[2] = f2bf(o2); op[3] = f2bf(o3);
  } else {
    float4 o4; o4.x = o0; o4.y = o1; o4.z = o2; o4.w = o3;
    reinterpret_cast<float4*>(out_f + (size_t)row * DMODEL)[t] = o4;
  }
}

// ---------------- f32 -> bf16 cast, 4 elems/thread ----------------
__global__ void castbf4(const float* __restrict__ in, unsigned short* __restrict__ out, int n4) {
  int i = blockIdx.x * 256 + threadIdx.x;
  if (i >= n4) return;
  float4 v = reinterpret_cast<const float4*>(in)[i];
  ushort4 o;
  o.x = f2bf(v.x); o.y = f2bf(v.y); o.z = f2bf(v.z); o.w = f2bf(v.w);
  reinterpret_cast<ushort4*>(out)[i] = o;
}

// ---------------- GEMM  C[M,N] = A[M,K] * B[N,K]^T,  LDS-staged (m97 structure) ----------
template<int EPI>
__global__ __launch_bounds__(256) void gemm_lds(
    const unsigned short* __restrict__ A, const unsigned short* __restrict__ B,
    int M, int N, int K,
    const float* __restrict__ b_in, const float* __restrict__ log_scale,
    unsigned short* __restrict__ outq, unsigned short* __restrict__ outk,
    unsigned short* __restrict__ outvt, unsigned short* __restrict__ outp,
    float* __restrict__ outf) {
  int nbn = N / 128;
  int bm = blockIdx.x / nbn, bn = blockIdx.x % nbn;
  int tid = threadIdx.x;
  int wid = tid >> 6, l = tid & 63;
  int wr = wid >> 1, wc = wid & 1;
  int row0 = bm * 128, col0 = bn * 128;
  int c16 = l & 15, g = l >> 4;
  int srow = l >> 2;
  int skb  = (l & 3) * 8;

  __shared__ __align__(16) unsigned short As[128 * 32];
  __shared__ __align__(16) unsigned short Bs[128 * 32];

  f32x4 acc[4][4];
  f32x4 z = {0.f, 0.f, 0.f, 0.f};
  #pragma unroll
  for (int i = 0; i < 4; ++i)
    #pragma unroll
    for (int j = 0; j < 4; ++j) acc[i][j] = z;

  for (int k0 = 0; k0 < K; k0 += 32) {
    #pragma unroll
    for (int qq = 0; qq < 2; ++qq) {
      int t = wid * 2 + qq;
      gload_lds16(A + (size_t)(row0 + t * 16 + srow) * K + k0 + skb, As + t * 512);
      gload_lds16(B + (size_t)(col0 + t * 16 + srow) * K + k0 + skb, Bs + t * 512);
    }
    __syncthreads();
    bf16x8 a[4], b[4];
    #pragma unroll
    for (int i = 0; i < 4; ++i)
      a[i] = *reinterpret_cast<const bf16x8*>(As + (wr * 64 + i * 16 + c16) * 32 + g * 8);
    #pragma unroll
    for (int j = 0; j < 4; ++j)
      b[j] = *reinterpret_cast<const bf16x8*>(Bs + (wc * 64 + j * 16 + c16) * 32 + g * 8);
    #pragma unroll
    for (int i = 0; i < 4; ++i)
      #pragma unroll
      for (int j = 0; j < 4; ++j)
        acc[i][j] = __builtin_amdgcn_mfma_f32_16x16x32_bf16(a[i], b[j], acc[i][j], 0, 0, 0);
    __syncthreads();
  }

  #pragma unroll
  for (int i = 0; i < 4; ++i) {
    #pragma unroll
    for (int j = 0; j < 4; ++j) {
      #pragma unroll
      for (int r = 0; r < 4; ++r) {
        int gi = row0 + wr * 64 + i * 16 + g * 4 + r;
        int n  = col0 + wc * 64 + j * 16 + c16;
        float val = acc[i][j][r];
        if constexpr (EPI == 0) {
          val += b_in[n];
          int sec = n >> 11, nn = n & 2047, hh = nn >> 7;
          if (sec == 0) {
            float qs = __expf(-2.f * log_scale[hh]) * 0.088388347648318447f; // 1/(s^2*sqrt(128))
            outq[(size_t)gi * DEXP + nn] = f2bf(val * qs);
          } else if (sec == 1) {
            outk[(size_t)gi * DEXP + nn] = f2bf(val);
          } else if (sec == 2) {
            outvt[(size_t)nn * SEQ + gi] = f2bf(val);   // V transposed: vt[h*128+d][i]
          } else {
            outp[(size_t)gi * DEXP + nn] = f2bf(val);
          }
        } else {
          outf[(size_t)gi * N + n] = val;
        }
      }
    }
  }
}

// ---------------- y head ----------------
__global__ __launch_bounds__(256) void yproj(const unsigned short* __restrict__ xn,
    const unsigned short* __restrict__ winbf, const float* __restrict__ b_in,
    float* __restrict__ sig_y) {
  int i = blockIdx.x;
  int t = threadIdx.x, wv = t >> 6, l = t & 63;
  const unsigned short* xr = xn + (size_t)i * DMODEL;
  for (int h = wv; h < NHEADS; h += 4) {
    const unsigned short* wr = winbf + (size_t)(4 * DEXP + h) * DMODEL;
    float s = 0.f;
    #pragma unroll
    for (int e = 0; e < 16; ++e) {
      int idx = l + 64 * e;
      s += bf2f(xr[idx]) * bf2f(wr[idx]);
    }
    #pragma unroll
    for (int m = 1; m < 64; m <<= 1) s += __shfl_xor(s, m, 64);
    if (l == 0) {
      float yv = s + b_in[4 * DEXP + h];
      sig_y[h * SEQ + i] = 1.f / (1.f + __expf(-yv));
    }
  }
}

// ---------------- inclusive scan of sig_y per head -> pos[h][i] ----------------
__global__ __launch_bounds__(256) void scan_kernel(const float* __restrict__ sig_y,
                                                   float* __restrict__ pos) {
  int h = blockIdx.x, t = threadIdx.x;
  const float* in = sig_y + (size_t)h * SEQ;
  float v[8], s = 0.f;
  #pragma unroll
  for (int e = 0; e < 8; ++e) { v[e] = in[t * 8 + e]; s += v[e]; }
  __shared__ float sh[256];
  sh[t] = s;
  __syncthreads();
  for (int off = 1; off < 256; off <<= 1) {
    float add = (t >= off) ? sh[t - off] : 0.f;
    __syncthreads();
    sh[t] += add;
    __syncthreads();
  }
  float run = sh[t] - s;
  float* op = pos + (size_t)h * SEQ;
  #pragma unroll
  for (int e = 0; e < 8; ++e) { run += v[e]; op[t * 8 + e] = run; }
}

// ---------------- smear ----------------
__global__ void smear_kernel(const unsigned short* __restrict__ projk,
    const float* __restrict__ smearf, unsigned short* __restrict__ ksm) {
  int idx = blockIdx.x * 256 + threadIdx.x;
  if (idx >= SEQ * DEXP) return;
  int i = idx >> 11, nn = idx & 2047, h = nn >> 7;
  float sf = 1.f / (1.f + __expf(-smearf[h]));
  float kc = bf2f(projk[idx]);
  float kp = (i > 0) ? bf2f(projk[idx - DEXP]) : 0.f;
  ksm[idx] = f2bf((1.f - sf) * kc + sf * kp);
}

// ---------------- flash attention v3: swapped-operand, lane-local softmax ----------------
// 256 blocks = 16 heads x 16 pair-groups; 8 waves. Wave (pr, parity) handles q-tile pair
// (pp, 127-pp) on jt = parity, parity+2, ... Swapped QK^T (mfma(K,Q) -> S^T) puts q-row
// c16 lane-local: softmax = in-lane reduce + 2 shfl levels; P^T assembled in-register via
// 4 u64 shuffles feeds swapped PV (mfma(V^T, P^T) -> O^T). No LDS in loop, no fences.
// Even/odd-jt partner waves merge (m,l,O) via LDS at the end.
__global__ __launch_bounds__(512, 2) void attn_kernel(
    const unsigned short* __restrict__ q, const unsigned short* __restrict__ ksm,
    const unsigned short* __restrict__ vt, const unsigned short* __restrict__ projp,
    const float* __restrict__ pos, unsigned short* __restrict__ ap) {
  int bid = blockIdx.x;
  int swz = (bid & 7) * 32 + (bid >> 3);   // bijective XCD swizzle: 2 heads per XCD
  int h = swz >> 4, pg = swz & 15;
  int tid = threadIdx.x;
  int wid = tid >> 6, l = tid & 63;
  int pr = wid & 3, parity = wid >> 2;
  int pp = pg * 4 + pr;
  int qtv[2] = { pp, 127 - pp };
  int c16 = l & 15, g = l >> 4;

  __shared__ float mlbuf[4][2][2][16];
  __shared__ float obuf[4][2][128][16];

  f32x4 z = {0.f, 0.f, 0.f, 0.f};
  bf16x8 qf[2][4];
  float pos_q[2], m_run[2], l_run[2];
  f32x4 oacc[2][8];
  int jtmax[2];
  #pragma unroll
  for (int s = 0; s < 2; ++s) {
    const unsigned short* qb = q + (size_t)(qtv[s] * 16 + c16) * DEXP + h * DHEAD + g * 8;
    #pragma unroll
    for (int f = 0; f < 4; ++f) qf[s][f] = *reinterpret_cast<const bf16x8*>(qb + f * 32);
    pos_q[s] = pos[h * SEQ + qtv[s] * 16 + c16];
    m_run[s] = -1e30f; l_run[s] = 0.f;
    #pragma unroll
    for (int nb = 0; nb < 8; ++nb) oacc[s][nb] = z;
    jtmax[s] = (qtv[s] * 16 + 15) >> 5;
  }

  for (int jt = parity; jt <= jtmax[1]; jt += 2) {
    int j0 = jt * 32;
    bf16x8 kf0[4], kf1[4];
    const unsigned short* kb = ksm + (size_t)(j0 + c16) * DEXP + h * DHEAD + g * 8;
    #pragma unroll
    for (int f = 0; f < 4; ++f) {
      kf0[f] = *reinterpret_cast<const bf16x8*>(kb + f * 32);
      kf1[f] = *reinterpret_cast<const bf16x8*>(kb + (size_t)16 * DEXP + f * 32);
    }
    bf16x8 vtf[8];
    const unsigned short* vb = vt + (size_t)(h * DHEAD + c16) * SEQ + j0 + g * 8;
    #pragma unroll
    for (int nb = 0; nb < 8; ++nb)
      vtf[nb] = *reinterpret_cast<const bf16x8*>(vb + (size_t)nb * 16 * SEQ);
    float4 pjlo = *reinterpret_cast<const float4*>(pos + h * SEQ + j0 + g * 4);
    float4 pjhi = *reinterpret_cast<const float4*>(pos + h * SEQ + j0 + 16 + g * 4);

    #pragma unroll
    for (int s = 0; s < 2; ++s) {
      if (jt > jtmax[s]) continue;   // wave-uniform (only s=0 can skip)
      f32x4 sLo = z, sHi = z;
      #pragma unroll
      for (int f = 0; f < 4; ++f) {
        sLo = __builtin_amdgcn_mfma_f32_16x16x32_bf16(kf0[f], qf[s][f], sLo, 0, 0, 0);
        sHi = __builtin_amdgcn_mfma_f32_16x16x32_bf16(kf1[f], qf[s][f], sHi, 0, 0, 0);
      }
      int qg = qtv[s] * 16 + c16;
      float a[8];
      float pj4[4] = { pjlo.x, pjlo.y, pjlo.z, pjlo.w };
      float pj4b[4] = { pjhi.x, pjhi.y, pjhi.z, pjhi.w };
      #pragma unroll
      for (int r = 0; r < 4; ++r) {
        int jlo = j0 + g * 4 + r, jhi = jlo + 16;
        a[r]     = sLo[r] - pos_q[s] + pj4[r]  + (jlo > qg ? -1e10f : 0.f);
        a[4 + r] = sHi[r] - pos_q[s] + pj4b[r] + (jhi > qg ? -1e10f : 0.f);
      }
      float mt = fmaxf(fmaxf(fmaxf(a[0], a[1]), fmaxf(a[2], a[3])),
                       fmaxf(fmaxf(a[4], a[5]), fmaxf(a[6], a[7])));
      mt = fmaxf(mt, __shfl_xor(mt, 16, 64));
      mt = fmaxf(mt, __shfl_xor(mt, 32, 64));
      float mn = fmaxf(m_run[s], mt);
      float alpha = __expf(m_run[s] - mn);
      m_run[s] = mn;
      float p[8], psum = 0.f;
      #pragma unroll
      for (int k = 0; k < 8; ++k) { p[k] = __expf(a[k] - mn); psum += p[k]; }
      psum += __shfl_xor(psum, 16, 64);
      psum += __shfl_xor(psum, 32, 64);
      l_run[s] = l_run[s] * alpha + psum;
      #pragma unroll
      for (int nb = 0; nb < 8; ++nb)
        #pragma unroll
        for (int r = 0; r < 4; ++r) oacc[s][nb][r] *= alpha;
      // P^T B-fragment in-register: lane (c16,g) needs P[j0+8g..8g+7][q=c16]
      unsigned long long AB = ((unsigned long long)pk2bf(p[2], p[3]) << 32) | pk2bf(p[0], p[1]);
      unsigned long long CD = ((unsigned long long)pk2bf(p[6], p[7]) << 32) | pk2bf(p[4], p[5]);
      int src = c16 + ((g & 1) << 5);
      unsigned long long t0 = __shfl(AB, src, 64);
      unsigned long long t1 = __shfl(AB, src + 16, 64);
      unsigned long long u0 = __shfl(CD, src, 64);
      unsigned long long u1 = __shfl(CD, src + 16, 64);
      union { unsigned long long u[2]; bf16x8 v; } pb;
      pb.u[0] = (g < 2) ? t0 : u0;
      pb.u[1] = (g < 2) ? t1 : u1;
      #pragma unroll
      for (int nb = 0; nb < 8; ++nb)
        oacc[s][nb] = __builtin_amdgcn_mfma_f32_16x16x32_bf16(vtf[nb], pb.v, oacc[s][nb], 0, 0, 0);
    }
  }

  // ---- merge even/odd partner waves via LDS ----
  if (parity == 0) {
    if (g == 0) {
      #pragma unroll
      for (int s = 0; s < 2; ++s) {
        mlbuf[pr][s][0][c16] = m_run[s];
        mlbuf[pr][s][1][c16] = l_run[s];
      }
    }
    #pragma unroll
    for (int s = 0; s < 2; ++s)
      #pragma unroll
      for (int nb = 0; nb < 8; ++nb)
        #pragma unroll
        for (int r = 0; r < 4; ++r)
          obuf[pr][s][nb * 16 + g * 4 + r][c16] = oacc[s][nb][r];
  }
  __syncthreads();
  if (parity == 1) {
    #pragma unroll
    for (int s = 0; s < 2; ++s) {
      float m0 = mlbuf[pr][s][0][c16], l0 = mlbuf[pr][s][1][c16];
      float M = fmaxf(m0, m_run[s]);
      float sc0 = __expf(m0 - M), sc1 = __expf(m_run[s] - M);
      float Li = 1.0f / (l0 * sc0 + l_run[s] * sc1);
      int row = qtv[s] * 16 + c16;
      #pragma unroll
      for (int nb = 0; nb < 8; ++nb) {
        #pragma unroll
        for (int r = 0; r < 4; ++r) {
          int d = nb * 16 + g * 4 + r;
          float o = (obuf[pr][s][d][c16] * sc0 + oacc[s][nb][r] * sc1) * Li;
          int nn = h * DHEAD + d;
          float pv = bf2f(projp[(size_t)row * DEXP + nn]);
          float si = pv / (1.f + __expf(-pv));
          ap[(size_t)row * DEXP + nn] = f2bf(si * o);
        }
      }
    }
  }
}

extern "C" void kernel_launch(void* const* d_in, const int* in_sizes, int n_in,
                              void* d_out, int out_size, void* d_ws, size_t ws_size,
                              hipStream_t stream) {
  const float* x         = (const float*)d_in[0];
  const float* W_in      = (const float*)d_in[1];
  const float* b_in      = (const float*)d_in[2];
  const float* in_ln_w   = (const float*)d_in[3];
  const float* in_ln_b   = (const float*)d_in[4];
  const float* W_out     = (const float*)d_in[5];
  const float* out_ln_w  = (const float*)d_in[6];
  const float* out_ln_b  = (const float*)d_in[7];
  const float* smearf    = (const float*)d_in[8];
  const float* log_scale = (const float*)d_in[9];
  float* out = (float*)d_out;

  char* ws = (char*)d_ws;
  size_t off = 0;
  auto alloc = [&](size_t bytes) -> void* {
    void* p = ws + off;
    off += (bytes + 255) & ~(size_t)255;
    return p;
  };
  unsigned short* xn     = (unsigned short*)alloc((size_t)SEQ * DMODEL * 2);
  unsigned short* winbf  = (unsigned short*)alloc((size_t)(4 * DEXP + NHEADS) * DMODEL * 2);
  unsigned short* woutbf = (unsigned short*)alloc((size_t)DMODEL * DEXP * 2);
  unsigned short* projq  = (unsigned short*)alloc((size_t)SEQ * DEXP * 2);
  unsigned short* projk  = (unsigned short*)alloc((size_t)SEQ * DEXP * 2);
  unsigned short* projp  = (unsigned short*)alloc((size_t)SEQ * DEXP * 2);
  unsigned short* vtb    = (unsigned short*)alloc((size_t)SEQ * DEXP * 2);
  unsigned short* ksm    = (unsigned short*)alloc((size_t)SEQ * DEXP * 2);
  unsigned short* apb    = (unsigned short*)alloc((size_t)SEQ * DEXP * 2);
  float* sig_y = (float*)alloc((size_t)NHEADS * SEQ * 4);
  float* posb  = (float*)alloc((size_t)NHEADS * SEQ * 4);
  float* outf  = (float*)alloc((size_t)SEQ * DMODEL * 4);

  int nwin4  = (4 * DEXP + NHEADS) * DMODEL / 4;
  int nwout4 = DMODEL * DEXP / 4;
  castbf4<<<(nwin4 + 255) / 256, 256, 0, stream>>>(W_in, winbf, nwin4);
  castbf4<<<(nwout4 + 255) / 256, 256, 0, stream>>>(W_out, woutbf, nwout4);
  ln_kernel<<<SEQ, 256, 0, stream>>>(x, in_ln_w, in_ln_b, xn, nullptr);
  gemm_lds<0><<<(SEQ / 128) * (4 * DEXP / 128), 256, 0, stream>>>(
      xn, winbf, SEQ, 4 * DEXP, DMODEL, b_in, log_scale, projq, projk, vtb, projp, nullptr);
  yproj<<<SEQ, 256, 0, stream>>>(xn, winbf, b_in, sig_y);
  scan_kernel<<<NHEADS, 256, 0, stream>>>(sig_y, posb);
  smear_kernel<<<(SEQ * DEXP + 255) / 256, 256, 0, stream>>>(projk, smearf, ksm);
  attn_kernel<<<256, 512, 0, stream>>>(projq, ksm, vtb, projp, posb, apb);
  gemm_lds<1><<<(SEQ / 128) * (DMODEL / 128), 256, 0, stream>>>(
      apb, woutbf, SEQ, DMODEL, DEXP, nullptr, nullptr, nullptr, nullptr, nullptr, nullptr, outf);
  ln_kernel<<<SEQ, 256, 0, stream>>>(outf, out_ln_w, out_ln_b, nullptr, out);
}

// Round 7
// 256.274 us; speedup vs baseline: 1.3174x; 1.1539x over previous
//
#include <hip/hip_runtime.h>
#include <hip/hip_bf16.h>
#include <cstdint>
#include <cstddef>

#define SEQ    2048
#define DMODEL 1024
#define DEXP   2048
#define NHEADS 16
#define DHEAD  128

typedef __bf16 bf16x8 __attribute__((ext_vector_type(8)));
typedef float  f32x4  __attribute__((ext_vector_type(4)));

__device__ __forceinline__ unsigned short f2bf(float f) {
  unsigned int u = __builtin_bit_cast(unsigned int, f);
  u = u + 0x7FFFu + ((u >> 16) & 1u);   // round-to-nearest-even
  return (unsigned short)(u >> 16);
}
__device__ __forceinline__ float bf2f(unsigned short h) {
  unsigned int u = ((unsigned int)h) << 16;
  return __builtin_bit_cast(float, u);
}
__device__ __forceinline__ unsigned int pk2bf(float a, float b) {
  return ((unsigned int)f2bf(b) << 16) | f2bf(a);
}

__device__ __forceinline__ void gload_lds16(const void* g, void* l) {
  __builtin_amdgcn_global_load_lds(
      (const __attribute__((address_space(1))) unsigned int*)g,
      (__attribute__((address_space(3))) unsigned int*)l, 16, 0, 0);
}

// ---------------- LayerNorm (one row of 1024 per block, 256 threads) ----------------
__global__ __launch_bounds__(256) void ln_kernel(const float* __restrict__ in,
    const float* __restrict__ gw, const float* __restrict__ gb,
    unsigned short* __restrict__ out_bf, float* __restrict__ out_f) {
  int row = blockIdx.x, t = threadIdx.x;
  const float4* ip = reinterpret_cast<const float4*>(in + (size_t)row * DMODEL);
  float4 v = ip[t];
  float s  = v.x + v.y + v.z + v.w;
  float ss = v.x*v.x + v.y*v.y + v.z*v.z + v.w*v.w;
  #pragma unroll
  for (int m = 1; m < 64; m <<= 1) { s += __shfl_xor(s, m, 64); ss += __shfl_xor(ss, m, 64); }
  __shared__ float sh[8];
  if ((t & 63) == 0) { sh[t >> 6] = s; sh[4 + (t >> 6)] = ss; }
  __syncthreads();
  s  = sh[0] + sh[1] + sh[2] + sh[3];
  ss = sh[4] + sh[5] + sh[6] + sh[7];
  float mu  = s * (1.0f / DMODEL);
  float var = ss * (1.0f / DMODEL) - mu * mu;
  float rs  = rsqrtf(var + 1e-5f);
  float4 w4 = reinterpret_cast<const float4*>(gw)[t];
  float4 b4 = reinterpret_cast<const float4*>(gb)[t];
  float o0 = (v.x - mu) * rs * w4.x + b4.x;
  float o1 = (v.y - mu) * rs * w4.y + b4.y;
  float o2 = (v.z - mu) * rs * w4.z + b4.z;
  float o3 = (v.w - mu) * rs * w4.w + b4.w;
  if (out_bf) {
    unsigned short* op = out_bf + (size_t)row * DMODEL + t * 4;
    op[0] = f2bf(o0); op[1] = f2bf(o1); op[2] = f2bf(o2); op[3] = f2bf(o3);
  } else {
    float4 o4; o4.x = o0; o4.y = o1; o4.z = o2; o4.w = o3;
    reinterpret_cast<float4*>(out_f + (size_t)row * DMODEL)[t] = o4;
  }
}

// ---------------- f32 -> bf16 cast, 4 elems/thread ----------------
__global__ void castbf4(const float* __restrict__ in, unsigned short* __restrict__ out, int n4) {
  int i = blockIdx.x * 256 + threadIdx.x;
  if (i >= n4) return;
  float4 v = reinterpret_cast<const float4*>(in)[i];
  ushort4 o;
  o.x = f2bf(v.x); o.y = f2bf(v.y); o.z = f2bf(v.z); o.w = f2bf(v.w);
  reinterpret_cast<ushort4*>(out)[i] = o;
}

// ---------------- GEMM  C[M,N] = A[M,K] * B[N,K]^T,  LDS-staged (m97 structure) ----------
template<int EPI>
__global__ __launch_bounds__(256) void gemm_lds(
    const unsigned short* __restrict__ A, const unsigned short* __restrict__ B,
    int M, int N, int K,
    const float* __restrict__ b_in, const float* __restrict__ log_scale,
    unsigned short* __restrict__ outq, unsigned short* __restrict__ outk,
    unsigned short* __restrict__ outvt, unsigned short* __restrict__ outp,
    float* __restrict__ outf) {
  int nbn = N / 128;
  int bm = blockIdx.x / nbn, bn = blockIdx.x % nbn;
  int tid = threadIdx.x;
  int wid = tid >> 6, l = tid & 63;
  int wr = wid >> 1, wc = wid & 1;
  int row0 = bm * 128, col0 = bn * 128;
  int c16 = l & 15, g = l >> 4;
  int srow = l >> 2;
  int skb  = (l & 3) * 8;

  __shared__ __align__(16) unsigned short As[128 * 32];
  __shared__ __align__(16) unsigned short Bs[128 * 32];

  f32x4 acc[4][4];
  f32x4 z = {0.f, 0.f, 0.f, 0.f};
  #pragma unroll
  for (int i = 0; i < 4; ++i)
    #pragma unroll
    for (int j = 0; j < 4; ++j) acc[i][j] = z;

  for (int k0 = 0; k0 < K; k0 += 32) {
    #pragma unroll
    for (int qq = 0; qq < 2; ++qq) {
      int t = wid * 2 + qq;
      gload_lds16(A + (size_t)(row0 + t * 16 + srow) * K + k0 + skb, As + t * 512);
      gload_lds16(B + (size_t)(col0 + t * 16 + srow) * K + k0 + skb, Bs + t * 512);
    }
    __syncthreads();
    bf16x8 a[4], b[4];
    #pragma unroll
    for (int i = 0; i < 4; ++i)
      a[i] = *reinterpret_cast<const bf16x8*>(As + (wr * 64 + i * 16 + c16) * 32 + g * 8);
    #pragma unroll
    for (int j = 0; j < 4; ++j)
      b[j] = *reinterpret_cast<const bf16x8*>(Bs + (wc * 64 + j * 16 + c16) * 32 + g * 8);
    #pragma unroll
    for (int i = 0; i < 4; ++i)
      #pragma unroll
      for (int j = 0; j < 4; ++j)
        acc[i][j] = __builtin_amdgcn_mfma_f32_16x16x32_bf16(a[i], b[j], acc[i][j], 0, 0, 0);
    __syncthreads();
  }

  #pragma unroll
  for (int i = 0; i < 4; ++i) {
    #pragma unroll
    for (int j = 0; j < 4; ++j) {
      #pragma unroll
      for (int r = 0; r < 4; ++r) {
        int gi = row0 + wr * 64 + i * 16 + g * 4 + r;
        int n  = col0 + wc * 64 + j * 16 + c16;
        float val = acc[i][j][r];
        if constexpr (EPI == 0) {
          val += b_in[n];
          int sec = n >> 11, nn = n & 2047, hh = nn >> 7;
          if (sec == 0) {
            float qs = __expf(-2.f * log_scale[hh]) * 0.088388347648318447f; // 1/(s^2*sqrt(128))
            outq[(size_t)gi * DEXP + nn] = f2bf(val * qs);
          } else if (sec == 1) {
            outk[(size_t)gi * DEXP + nn] = f2bf(val);
          } else if (sec == 2) {
            outvt[(size_t)nn * SEQ + gi] = f2bf(val);   // V transposed: vt[h*128+d][i]
          } else {
            outp[(size_t)gi * DEXP + nn] = f2bf(val);
          }
        } else {
          outf[(size_t)gi * N + n] = val;
        }
      }
    }
  }
}

// ---------------- y head ----------------
__global__ __launch_bounds__(256) void yproj(const unsigned short* __restrict__ xn,
    const unsigned short* __restrict__ winbf, const float* __restrict__ b_in,
    float* __restrict__ sig_y) {
  int i = blockIdx.x;
  int t = threadIdx.x, wv = t >> 6, l = t & 63;
  const unsigned short* xr = xn + (size_t)i * DMODEL;
  for (int h = wv; h < NHEADS; h += 4) {
    const unsigned short* wr = winbf + (size_t)(4 * DEXP + h) * DMODEL;
    float s = 0.f;
    #pragma unroll
    for (int e = 0; e < 16; ++e) {
      int idx = l + 64 * e;
      s += bf2f(xr[idx]) * bf2f(wr[idx]);
    }
    #pragma unroll
    for (int m = 1; m < 64; m <<= 1) s += __shfl_xor(s, m, 64);
    if (l == 0) {
      float yv = s + b_in[4 * DEXP + h];
      sig_y[h * SEQ + i] = 1.f / (1.f + __expf(-yv));
    }
  }
}

// ---------------- inclusive scan of sig_y per head -> pos[h][i] ----------------
__global__ __launch_bounds__(256) void scan_kernel(const float* __restrict__ sig_y,
                                                   float* __restrict__ pos) {
  int h = blockIdx.x, t = threadIdx.x;
  const float* in = sig_y + (size_t)h * SEQ;
  float v[8], s = 0.f;
  #pragma unroll
  for (int e = 0; e < 8; ++e) { v[e] = in[t * 8 + e]; s += v[e]; }
  __shared__ float sh[256];
  sh[t] = s;
  __syncthreads();
  for (int off = 1; off < 256; off <<= 1) {
    float add = (t >= off) ? sh[t - off] : 0.f;
    __syncthreads();
    sh[t] += add;
    __syncthreads();
  }
  float run = sh[t] - s;
  float* op = pos + (size_t)h * SEQ;
  #pragma unroll
  for (int e = 0; e < 8; ++e) { run += v[e]; op[t * 8 + e] = run; }
}

// ---------------- smear ----------------
__global__ void smear_kernel(const unsigned short* __restrict__ projk,
    const float* __restrict__ smearf, unsigned short* __restrict__ ksm) {
  int idx = blockIdx.x * 256 + threadIdx.x;
  if (idx >= SEQ * DEXP) return;
  int i = idx >> 11, nn = idx & 2047, h = nn >> 7;
  float sf = 1.f / (1.f + __expf(-smearf[h]));
  float kc = bf2f(projk[idx]);
  float kp = (i > 0) ? bf2f(projk[idx - DEXP]) : 0.f;
  ksm[idx] = f2bf((1.f - sf) * kc + sf * kp);
}

// ---------------- flash attention v4: block-level LDS K/V staging ----------------
// Block = (head, 128-row q-chunk): 256 blocks, 8 waves x 16 q-rows. Per KV-tile of 64:
// all 512 threads stage K[64][128] and V^T[128][64] into LDS (XOR-swizzled via
// pre-swizzled GLOBAL source, linear LDS dest: rule "both-sides-or-neither").
// Compute keeps the swapped-MFMA lane-local softmax: mfma(K,Q) -> S^T (q = lane&15),
// in-register P^T assembly via u64 shuffles, mfma(V^T, P^T) -> O^T.
__global__ __launch_bounds__(512) void attn_kernel(
    const unsigned short* __restrict__ q, const unsigned short* __restrict__ ksm,
    const unsigned short* __restrict__ vt, const unsigned short* __restrict__ projp,
    const float* __restrict__ pos, unsigned short* __restrict__ ap) {
  int bid = blockIdx.x;
  int swz = (bid & 7) * 32 + (bid >> 3);   // bijective XCD swizzle: 2 heads per XCD
  int h = swz >> 4, qc = swz & 15;
  int q0 = qc * 128;
  int tid = threadIdx.x;
  int w = tid >> 6, l = tid & 63;
  int c16 = l & 15, g = l >> 4;

  __shared__ __align__(16) unsigned short Ks[64 * 128];   // 16KB, rows 256B, swizzled
  __shared__ __align__(16) unsigned short Vs[128 * 64];   // 16KB (V^T), rows 128B, swizzled

  int qrow = q0 + w * 16 + c16;
  bf16x8 qf[4];
  {
    const unsigned short* qb = q + (size_t)qrow * DEXP + h * DHEAD + g * 8;
    #pragma unroll
    for (int f = 0; f < 4; ++f) qf[f] = *reinterpret_cast<const bf16x8*>(qb + f * 32);
  }
  float pos_q = pos[h * SEQ + qrow];
  float m_run = -1e30f, l_run = 0.f;
  f32x4 z = {0.f, 0.f, 0.f, 0.f};
  f32x4 oacc[8];
  #pragma unroll
  for (int d = 0; d < 8; ++d) oacc[d] = z;

  int ntiles = 2 * qc + 2;
  int wmax = q0 + w * 16 + 15;   // last row this warp needs
  int kch = tid & 15;            // K staging: 16 chunks of 16B per 256B row
  int krow0 = tid >> 4;          //   rows 0..31 per round
  int vch = tid & 7;             // V staging: 8 chunks of 16B per 128B row
  int vrow0 = tid >> 3;          //   rows 0..63 per round

  for (int t = 0; t < ntiles; ++t) {
    int j0 = t * 64;
    // ---- stage K,V tile (linear LDS dest, inverse-swizzled global source) ----
    #pragma unroll
    for (int rr = 0; rr < 2; ++rr) {
      int row = rr * 32 + krow0;
      gload_lds16(ksm + (size_t)(j0 + row) * DEXP + h * DHEAD + ((kch ^ (row & 7)) * 8),
                  (char*)Ks + rr * 8192 + tid * 16);
    }
    #pragma unroll
    for (int rr = 0; rr < 2; ++rr) {
      int row = rr * 64 + vrow0;
      gload_lds16(vt + (size_t)(h * DHEAD + row) * SEQ + j0 + ((vch ^ (row & 7)) * 8),
                  (char*)Vs + rr * 8192 + tid * 16);
    }
    __syncthreads();   // drains vmcnt -> LDS visible

    if (j0 <= wmax) {  // wave-uniform causal skip
      // ---- QK^T (swapped): S^T[j][q=c16], 4 j-subtiles ----
      f32x4 sT[4];
      #pragma unroll
      for (int sub = 0; sub < 4; ++sub) {
        sT[sub] = z;
        int krow = sub * 16 + c16;
        const char* kb = (const char*)Ks + krow * 256;
        #pragma unroll
        for (int f = 0; f < 4; ++f) {
          int cb = (f * 64 + g * 16) ^ ((c16 & 7) << 4);
          bf16x8 kf = *reinterpret_cast<const bf16x8*>(kb + cb);
          sT[sub] = __builtin_amdgcn_mfma_f32_16x16x32_bf16(kf, qf[f], sT[sub], 0, 0, 0);
        }
      }
      // ---- mask + lane-local online softmax ----
      float a[4][4], mt = -1e30f;
      #pragma unroll
      for (int sub = 0; sub < 4; ++sub) {
        float4 pj = *reinterpret_cast<const float4*>(pos + h * SEQ + j0 + sub * 16 + g * 4);
        float pj4[4] = { pj.x, pj.y, pj.z, pj.w };
        #pragma unroll
        for (int r = 0; r < 4; ++r) {
          int j = j0 + sub * 16 + g * 4 + r;
          a[sub][r] = sT[sub][r] - pos_q + pj4[r] + (j > qrow ? -1e10f : 0.f);
          mt = fmaxf(mt, a[sub][r]);
        }
      }
      mt = fmaxf(mt, __shfl_xor(mt, 16, 64));
      mt = fmaxf(mt, __shfl_xor(mt, 32, 64));
      float mn = fmaxf(m_run, mt);
      float alpha = __expf(m_run - mn);
      m_run = mn;
      float p[4][4], psum = 0.f;
      #pragma unroll
      for (int sub = 0; sub < 4; ++sub)
        #pragma unroll
        for (int r = 0; r < 4; ++r) { p[sub][r] = __expf(a[sub][r] - mn); psum += p[sub][r]; }
      psum += __shfl_xor(psum, 16, 64);
      psum += __shfl_xor(psum, 32, 64);
      l_run = l_run * alpha + psum;
      #pragma unroll
      for (int d = 0; d < 8; ++d)
        #pragma unroll
        for (int r = 0; r < 4; ++r) oacc[d][r] *= alpha;
      // ---- P^T B-fragments in-register ----
      unsigned long long pk[4];
      #pragma unroll
      for (int sub = 0; sub < 4; ++sub)
        pk[sub] = ((unsigned long long)pk2bf(p[sub][2], p[sub][3]) << 32)
                |  pk2bf(p[sub][0], p[sub][1]);
      int src = c16 + ((g & 1) << 5);
      union { unsigned long long u[2]; bf16x8 v; } pb[2];
      #pragma unroll
      for (int js = 0; js < 2; ++js) {
        unsigned long long t0 = __shfl(pk[2 * js],     src, 64);
        unsigned long long t1 = __shfl(pk[2 * js],     src + 16, 64);
        unsigned long long u0 = __shfl(pk[2 * js + 1], src, 64);
        unsigned long long u1 = __shfl(pk[2 * js + 1], src + 16, 64);
        pb[js].u[0] = (g < 2) ? t0 : u0;
        pb[js].u[1] = (g < 2) ? t1 : u1;
      }
      // ---- PV (swapped): O^T[d][q] += V^T[d][j] P^T[j][q] ----
      #pragma unroll
      for (int d = 0; d < 8; ++d) {
        int vrow = d * 16 + c16;
        const char* vb = (const char*)Vs + vrow * 128;
        #pragma unroll
        for (int js = 0; js < 2; ++js) {
          int cb = (js * 64 + g * 16) ^ ((c16 & 7) << 4);
          bf16x8 vf = *reinterpret_cast<const bf16x8*>(vb + cb);
          oacc[d] = __builtin_amdgcn_mfma_f32_16x16x32_bf16(vf, pb[js].v, oacc[d], 0, 0, 0);
        }
      }
    }
    __syncthreads();   // protect LDS before next stage
  }

  // ---- epilogue: divide by l, silu-gate, store ----
  float inv_l = 1.0f / l_run;
  #pragma unroll
  for (int d = 0; d < 8; ++d) {
    int nn = h * DHEAD + d * 16 + g * 4;
    ushort4 pv4 = *reinterpret_cast<const ushort4*>(projp + (size_t)qrow * DEXP + nn);
    ushort4 o4;
    unsigned short* pvp = reinterpret_cast<unsigned short*>(&pv4);
    unsigned short* op  = reinterpret_cast<unsigned short*>(&o4);
    #pragma unroll
    for (int r = 0; r < 4; ++r) {
      float o = oacc[d][r] * inv_l;
      float pv = bf2f(pvp[r]);
      float si = pv / (1.f + __expf(-pv));
      op[r] = f2bf(si * o);
    }
    *reinterpret_cast<ushort4*>(ap + (size_t)qrow * DEXP + nn) = o4;
  }
}

extern "C" void kernel_launch(void* const* d_in, const int* in_sizes, int n_in,
                              void* d_out, int out_size, void* d_ws, size_t ws_size,
                              hipStream_t stream) {
  const float* x         = (const float*)d_in[0];
  const float* W_in      = (const float*)d_in[1];
  const float* b_in      = (const float*)d_in[2];
  const float* in_ln_w   = (const float*)d_in[3];
  const float* in_ln_b   = (const float*)d_in[4];
  const float* W_out     = (const float*)d_in[5];
  const float* out_ln_w  = (const float*)d_in[6];
  const float* out_ln_b  = (const float*)d_in[7];
  const float* smearf    = (const float*)d_in[8];
  const float* log_scale = (const float*)d_in[9];
  float* out = (float*)d_out;

  char* ws = (char*)d_ws;
  size_t off = 0;
  auto alloc = [&](size_t bytes) -> void* {
    void* p = ws + off;
    off += (bytes + 255) & ~(size_t)255;
    return p;
  };
  unsigned short* xn     = (unsigned short*)alloc((size_t)SEQ * DMODEL * 2);
  unsigned short* winbf  = (unsigned short*)alloc((size_t)(4 * DEXP + NHEADS) * DMODEL * 2);
  unsigned short* woutbf = (unsigned short*)alloc((size_t)DMODEL * DEXP * 2);
  unsigned short* projq  = (unsigned short*)alloc((size_t)SEQ * DEXP * 2);
  unsigned short* projk  = (unsigned short*)alloc((size_t)SEQ * DEXP * 2);
  unsigned short* projp  = (unsigned short*)alloc((size_t)SEQ * DEXP * 2);
  unsigned short* vtb    = (unsigned short*)alloc((size_t)SEQ * DEXP * 2);
  unsigned short* ksm    = (unsigned short*)alloc((size_t)SEQ * DEXP * 2);
  unsigned short* apb    = (unsigned short*)alloc((size_t)SEQ * DEXP * 2);
  float* sig_y = (float*)alloc((size_t)NHEADS * SEQ * 4);
  float* posb  = (float*)alloc((size_t)NHEADS * SEQ * 4);
  float* outf  = (float*)alloc((size_t)SEQ * DMODEL * 4);

  int nwin4  = (4 * DEXP + NHEADS) * DMODEL / 4;
  int nwout4 = DMODEL * DEXP / 4;
  castbf4<<<(nwin4 + 255) / 256, 256, 0, stream>>>(W_in, winbf, nwin4);
  castbf4<<<(nwout4 + 255) / 256, 256, 0, stream>>>(W_out, woutbf, nwout4);
  ln_kernel<<<SEQ, 256, 0, stream>>>(x, in_ln_w, in_ln_b, xn, nullptr);
  gemm_lds<0><<<(SEQ / 128) * (4 * DEXP / 128), 256, 0, stream>>>(
      xn, winbf, SEQ, 4 * DEXP, DMODEL, b_in, log_scale, projq, projk, vtb, projp, nullptr);
  yproj<<<SEQ, 256, 0, stream>>>(xn, winbf, b_in, sig_y);
  scan_kernel<<<NHEADS, 256, 0, stream>>>(sig_y, posb);
  smear_kernel<<<(SEQ * DEXP + 255) / 256, 256, 0, stream>>>(projk, smearf, ksm);
  attn_kernel<<<256, 512, 0, stream>>>(projq, ksm, vtb, projp, posb, apb);
  gemm_lds<1><<<(SEQ / 128) * (DMODEL / 128), 256, 0, stream>>>(
      apb, woutbf, SEQ, DMODEL, DEXP, nullptr, nullptr, nullptr, nullptr, nullptr, nullptr, outf);
  ln_kernel<<<SEQ, 256, 0, stream>>>(outf, out_ln_w, out_ln_b, nullptr, out);
}